// Round 1
// baseline (2673.422 us; speedup 1.0000x reference)
//
#include <hip/hip_runtime.h>
#include <hip/hip_bf16.h>
#include <stdint.h>

#define BB 8
#define NN 4096
#define DD 64
#define GG 32
#define KK 16

// ---------------------------------------------------------------------------
// KNN: per-thread query point, stable top-17 of (dist,index) as packed u64.
// dist computed with the reference's arithmetic shape:
//   sq = (x*x + y*y) + z*z   (mul/add, round-to-nearest)
//   dist = (sq_i + sq_j) - 2*dot,  dot = fma chain
// Rank 0 is always self (dist ~ 0); output ranks 1..16.
// ---------------------------------------------------------------------------
__global__ __launch_bounds__(128)
void knn_kernel(const float* __restrict__ pos, int* __restrict__ out_idx) {
    __shared__ __align__(16) float spx[NN];
    __shared__ __align__(16) float spy[NN];
    __shared__ __align__(16) float spz[NN];

    const int b = blockIdx.x >> 5;      // 32 chunks of 128 points per batch
    const int chunk = blockIdx.x & 31;
    const int tid = threadIdx.x;
    const float* pb = pos + (size_t)b * NN * 3;

    for (int t = tid; t < NN; t += 128) {
        spx[t] = pb[t * 3 + 0];
        spy[t] = pb[t * 3 + 1];
        spz[t] = pb[t * 3 + 2];
    }
    __syncthreads();

    const int i = chunk * 128 + tid;
    const float xi = spx[i], yi = spy[i], zi = spz[i];
    const float sqi = __fadd_rn(__fadd_rn(__fmul_rn(xi, xi), __fmul_rn(yi, yi)),
                                __fmul_rn(zi, zi));

    // sentinel: dist=+INF, idx=0xFFFFFFFF  (real dists are finite, so this sorts last)
    unsigned long long key[17];
#pragma unroll
    for (int q = 0; q < 17; ++q) key[q] = 0x7F800000FFFFFFFFull;

    for (int j0 = 0; j0 < NN; j0 += 4) {
        float4 vx = *(const float4*)&spx[j0];
        float4 vy = *(const float4*)&spy[j0];
        float4 vz = *(const float4*)&spz[j0];
        float d[4];
        {
            const float jx[4] = {vx.x, vx.y, vx.z, vx.w};
            const float jy[4] = {vy.x, vy.y, vy.z, vy.w};
            const float jz[4] = {vz.x, vz.y, vz.z, vz.w};
#pragma unroll
            for (int u = 0; u < 4; ++u) {
                float sqj = __fadd_rn(__fadd_rn(__fmul_rn(jx[u], jx[u]),
                                                __fmul_rn(jy[u], jy[u])),
                                      __fmul_rn(jz[u], jz[u]));
                float dot = __fmaf_rn(jz[u], zi, __fmaf_rn(jy[u], yi, __fmul_rn(jx[u], xi)));
                float dd_ = __fsub_rn(__fadd_rn(sqi, sqj), __fmul_rn(2.0f, dot));
                d[u] = fmaxf(dd_, 0.0f);   // only self can go (barely) negative
            }
        }
        float mall = fminf(fminf(d[0], d[1]), fminf(d[2], d[3]));
        float thr = __uint_as_float((unsigned)(key[16] >> 32));
        if (mall <= thr) {   // <= so exact boundary ties still hit the exact u64 test
#pragma unroll
            for (int u = 0; u < 4; ++u) {
                unsigned long long ck =
                    ((unsigned long long)__float_as_uint(d[u]) << 32) | (unsigned)(j0 + u);
                if (ck < key[16]) {
#pragma unroll
                    for (int q = 0; q < 17; ++q) {
                        bool less = ck < key[q];
                        unsigned long long tmp = less ? key[q] : ck;
                        key[q] = less ? ck : key[q];
                        ck = tmp;
                    }
                }
            }
        }
    }

    int* op = out_idx + ((size_t)b * NN + i) * KK;
#pragma unroll
    for (int q = 1; q <= KK; ++q) op[q - 1] = (int)(unsigned)(key[q] & 0xFFFFFFFFu);
}

// ---------------------------------------------------------------------------
// Fused per-point pipeline. One 256-thread block per (b,n).
// edge(16x192) -> h1(16x256) -> h2(16x32) -> mid(16x32) -> y(16x128)
// gate(128) from mean_k, y*=gate, z = y@Wlast (16x32), out = max_k [z|y] (160)
// y channel layout: [mid 0..31 | h2 32..63 | x 64..127]
// ---------------------------------------------------------------------------
__global__ __launch_bounds__(256)
void fused_kernel(const float* __restrict__ x, const int* __restrict__ knn,
                  const float* __restrict__ W1, const float* __restrict__ b1,
                  const float* __restrict__ W2, const float* __restrict__ b2,
                  const float* __restrict__ Wmid, const float* __restrict__ bmid,
                  const float* __restrict__ Wg, const float* __restrict__ bg,
                  const float* __restrict__ Wlast, const float* __restrict__ blast,
                  float* __restrict__ out) {
    __shared__ __align__(16) float s_edge[KK][192];
    __shared__ __align__(16) float s_h1[KK][256];
    __shared__ __align__(16) float s_y[KK][128];
    __shared__ __align__(16) float s_z[KK][GG];
    __shared__ float s_ym[128];
    __shared__ float s_gate[128];

    const int p = blockIdx.x;           // 0..B*N-1
    const int b = p >> 12;
    const int n = p & 4095;
    const int t = threadIdx.x;

    // ---- stage edge = [x, xn, xn-x]; also x part of y ----
    {
        const int k = t >> 4;           // 0..15
        const int c4 = (t & 15) * 4;    // 0..60
        const float* xrow = x + ((size_t)(b * NN + n)) * DD;
        const int nb = knn[(size_t)p * KK + k];
        const float* nrow = x + ((size_t)b * NN + nb) * DD;
        float4 xi = *(const float4*)(xrow + c4);
        float4 xn = *(const float4*)(nrow + c4);
        *(float4*)&s_edge[k][c4] = xi;
        *(float4*)&s_edge[k][64 + c4] = xn;
        float4 df;
        df.x = xn.x - xi.x; df.y = xn.y - xi.y; df.z = xn.z - xi.z; df.w = xn.w - xi.w;
        *(float4*)&s_edge[k][128 + c4] = df;
        *(float4*)&s_y[k][64 + c4] = xi;
    }
    __syncthreads();

    // ---- h1 = relu(edge @ W1 + b1) : (16,192)@(192,256) ----
    {
        const int c4 = (t & 63) * 4;    // 0..252
        const int k4 = (t >> 6) * 4;    // 0,4,8,12
        float acc[4][4];
        const float4 bias = *(const float4*)(b1 + c4);
#pragma unroll
        for (int kk = 0; kk < 4; ++kk) {
            acc[kk][0] = bias.x; acc[kk][1] = bias.y;
            acc[kk][2] = bias.z; acc[kk][3] = bias.w;
        }
        for (int r = 0; r < 192; ++r) {
            float4 w = *(const float4*)(W1 + (size_t)r * 256 + c4);
#pragma unroll
            for (int kk = 0; kk < 4; ++kk) {
                float e = s_edge[k4 + kk][r];
                acc[kk][0] = fmaf(e, w.x, acc[kk][0]);
                acc[kk][1] = fmaf(e, w.y, acc[kk][1]);
                acc[kk][2] = fmaf(e, w.z, acc[kk][2]);
                acc[kk][3] = fmaf(e, w.w, acc[kk][3]);
            }
        }
#pragma unroll
        for (int kk = 0; kk < 4; ++kk) {
            float4 v;
            v.x = fmaxf(acc[kk][0], 0.f); v.y = fmaxf(acc[kk][1], 0.f);
            v.z = fmaxf(acc[kk][2], 0.f); v.w = fmaxf(acc[kk][3], 0.f);
            *(float4*)&s_h1[k4 + kk][c4] = v;
        }
    }
    __syncthreads();

    // ---- h2 = relu(h1 @ W2 + b2) -> s_y[k][32+c] ----
    {
        const int c = t & 31;
        const int k = t >> 5;           // 0..7, also handles k+8
        float a0 = b2[c], a1 = b2[c];
        for (int r = 0; r < 256; ++r) {
            float w = W2[(size_t)r * 32 + c];
            a0 = fmaf(s_h1[k][r], w, a0);
            a1 = fmaf(s_h1[k + 8][r], w, a1);
        }
        s_y[k][32 + c] = fmaxf(a0, 0.f);
        s_y[k + 8][32 + c] = fmaxf(a1, 0.f);
    }
    __syncthreads();

    // ---- mid = relu([h2,x] @ Wmid + bmid) -> s_y[k][c] ----
    {
        const int c = t & 31;
        const int k = t >> 5;
        float a0 = bmid[c], a1 = bmid[c];
        for (int r = 0; r < 96; ++r) {
            float w = Wmid[(size_t)r * 32 + c];
            a0 = fmaf(s_y[k][32 + r], w, a0);
            a1 = fmaf(s_y[k + 8][32 + r], w, a1);
        }
        s_y[k][c] = fmaxf(a0, 0.f);
        s_y[k + 8][c] = fmaxf(a1, 0.f);
    }
    __syncthreads();

    // ---- ym = mean_k y ----
    if (t < 128) {
        float s = 0.f;
#pragma unroll
        for (int k = 0; k < 16; ++k) s += s_y[k][t];
        s_ym[t] = s * 0.0625f;
    }
    __syncthreads();

    // ---- gate = sigmoid(ym @ Wg + bg) ----
    if (t < 128) {
        float a = bg[t];
        for (int r = 0; r < 128; ++r) a = fmaf(s_ym[r], Wg[(size_t)r * 128 + t], a);
        s_gate[t] = 1.0f / (1.0f + __expf(-a));
    }
    __syncthreads();

    // ---- y *= gate ----
    {
        const int k = t >> 4;
        const int c0 = (t & 15) * 8;
#pragma unroll
        for (int u = 0; u < 8; ++u) s_y[k][c0 + u] *= s_gate[c0 + u];
    }
    __syncthreads();

    // ---- z = y @ Wlast + blast ----
    {
        const int c = t & 31;
        const int k = t >> 5;
        float a0 = blast[c], a1 = blast[c];
        for (int r = 0; r < 128; ++r) {
            float w = Wlast[(size_t)r * 32 + c];
            a0 = fmaf(s_y[k][r], w, a0);
            a1 = fmaf(s_y[k + 8][r], w, a1);
        }
        s_z[k][c] = a0;
        s_z[k + 8][c] = a1;
    }
    __syncthreads();

    // ---- out = max_k [z | y] ----
    if (t < 160) {
        float m;
        if (t < 32) {
            m = s_z[0][t];
#pragma unroll
            for (int k = 1; k < 16; ++k) m = fmaxf(m, s_z[k][t]);
        } else {
            const int c = t - 32;
            m = s_y[0][c];
#pragma unroll
            for (int k = 1; k < 16; ++k) m = fmaxf(m, s_y[k][c]);
        }
        out[(size_t)p * 160 + t] = m;
    }
}

extern "C" void kernel_launch(void* const* d_in, const int* in_sizes, int n_in,
                              void* d_out, int out_size, void* d_ws, size_t ws_size,
                              hipStream_t stream) {
    const float* x     = (const float*)d_in[0];
    const float* pos   = (const float*)d_in[1];
    const float* W1    = (const float*)d_in[2];
    const float* b1    = (const float*)d_in[3];
    const float* W2    = (const float*)d_in[4];
    const float* b2    = (const float*)d_in[5];
    const float* Wmid  = (const float*)d_in[6];
    const float* bmid  = (const float*)d_in[7];
    const float* Wg    = (const float*)d_in[8];
    const float* bg    = (const float*)d_in[9];
    const float* Wlast = (const float*)d_in[10];
    const float* blast = (const float*)d_in[11];
    float* out = (float*)d_out;
    int* idx = (int*)d_ws;   // B*N*K ints = 2 MB

    knn_kernel<<<dim3(BB * 32), dim3(128), 0, stream>>>(pos, idx);
    fused_kernel<<<dim3(BB * NN), dim3(256), 0, stream>>>(
        x, idx, W1, b1, W2, b2, Wmid, bmid, Wg, bg, Wlast, blast, out);
}

// Round 2
// 1070.401 us; speedup vs baseline: 2.4976x; 2.4976x over previous
//
#include <hip/hip_runtime.h>
#include <stdint.h>

#define BB 8
#define NN 4096

typedef float f32x4 __attribute__((ext_vector_type(4)));
typedef short bf16x8 __attribute__((ext_vector_type(8)));
#define MFMA16(a, b, c) __builtin_amdgcn_mfma_f32_16x16x32_bf16(a, b, c, 0, 0, 0)

static __device__ __forceinline__ short f2b(float f) {
    unsigned u = __float_as_uint(f);
    unsigned r = (u + 0x7FFFu + ((u >> 16) & 1u)) >> 16;   // RNE, finite values
    return (short)r;
}
static __device__ __forceinline__ float b2f(short s) {
    return __uint_as_float(((unsigned)(unsigned short)s) << 16);
}

// ---------------------------------------------------------------------------
// Prep: planar pos + sq (exact reference arithmetic), weights -> bf16,
// transposed to [col][k] so MFMA B-fragments are contiguous 16B loads.
// ---------------------------------------------------------------------------
__global__ __launch_bounds__(256)
void prep_kernel(const float* __restrict__ pos,
                 const float* __restrict__ W1, const float* __restrict__ W2,
                 const float* __restrict__ Wmid, const float* __restrict__ Wlast,
                 float* __restrict__ px, float* __restrict__ py,
                 float* __restrict__ pz, float* __restrict__ sq,
                 short* __restrict__ W1T, short* __restrict__ W2T,
                 short* __restrict__ WmidT, short* __restrict__ WlastT) {
    int t = blockIdx.x * 256 + threadIdx.x;
    if (t < 32768) {
        float x = pos[t * 3 + 0], y = pos[t * 3 + 1], z = pos[t * 3 + 2];
        px[t] = x; py[t] = y; pz[t] = z;
        sq[t] = __fadd_rn(__fadd_rn(__fmul_rn(x, x), __fmul_rn(y, y)), __fmul_rn(z, z));
    } else if (t < 81920) {          // W1T[col*192+k], col<256,k<192
        int e = t - 32768; int col = e / 192, k = e - col * 192;
        W1T[e] = f2b(W1[(size_t)k * 256 + col]);
    } else if (t < 90112) {          // W2T[col*256+k], col<32,k<256
        int e = t - 81920; int col = e >> 8, k = e & 255;
        W2T[e] = f2b(W2[(size_t)k * 32 + col]);
    } else if (t < 93184) {          // WmidT[col*96+k]
        int e = t - 90112; int col = e / 96, k = e - col * 96;
        WmidT[e] = f2b(Wmid[(size_t)k * 32 + col]);
    } else if (t < 97280) {          // WlastT[col*128+k]
        int e = t - 93184; int col = e >> 7, k = e & 127;
        WlastT[e] = f2b(Wlast[(size_t)k * 32 + col]);
    }
}

// ---------------------------------------------------------------------------
// KNN v2: one wave per query. Exact stable top-17 via:
//  A) 64 dists/lane -> LDS [lane][65] (+ lane min)
//  B) tau = 17th-smallest of 64 lane minima  (=> count(d<=tau) >= 17, exact)
//  C) ballot-compact survivors (u64 keys)
//  D) 17x wave-extract-min of (dist_bits<<32 | idx)  == stable top-k
// Distance arithmetic bit-identical to the round-1 passing kernel.
// ---------------------------------------------------------------------------
__global__ __launch_bounds__(64)
void knn2_kernel(const float* __restrict__ px, const float* __restrict__ py,
                 const float* __restrict__ pz, const float* __restrict__ sq,
                 int* __restrict__ out_idx) {
    __shared__ float sd[64 * 65];
    __shared__ unsigned long long comp[512];

    const int q = blockIdx.x;
    const int b = q >> 12, i = q & 4095;
    const int l = threadIdx.x;
    const int base = b << 12;
    const float INF = __uint_as_float(0x7F800000u);

    const float qx = px[base + i], qy = py[base + i], qz = pz[base + i];
    const float qsq = sq[base + i];

    float lmin = INF;
#pragma unroll 4
    for (int t = 0; t < 64; ++t) {
        int j = (t << 6) + l;
        float jx = px[base + j], jy = py[base + j], jz = pz[base + j];
        float sj = sq[base + j];
        float dot = __fmaf_rn(jz, qz, __fmaf_rn(jy, qy, __fmul_rn(jx, qx)));
        float d = __fsub_rn(__fadd_rn(qsq, sj), __fmul_rn(2.0f, dot));
        d = fmaxf(d, 0.0f);
        sd[l * 65 + t] = d;
        lmin = fminf(lmin, d);
    }

    // B) 17th smallest of lane minima
    float cur = lmin, tau = INF;
    for (int r = 0; r < 17; ++r) {
        float m = cur;
#pragma unroll
        for (int o = 1; o < 64; o <<= 1) m = fminf(m, __shfl_xor(m, o));
        unsigned long long bal = __ballot(cur == m);
        if (l == (__ffsll((unsigned long long)bal) - 1)) cur = INF;
        tau = m;
    }

    // C) compact
    int cbase = 0;
    const unsigned long long ltm = (l == 0) ? 0ull : ((~0ull) >> (64 - l));
    for (int t = 0; t < 64; ++t) {
        float d = sd[l * 65 + t];
        bool pr = (d <= tau);
        unsigned long long bal = __ballot(pr);
        if (pr) {
            int ps = cbase + __popcll(bal & ltm);
            if (ps < 512)
                comp[ps] = ((unsigned long long)__float_as_uint(d) << 32) |
                           (unsigned)((t << 6) + l);
        }
        cbase += __popcll(bal);
    }
    if (cbase > 512) cbase = 512;

    // D) extract stable top-17
    const unsigned long long INFK = ~0ull;
    unsigned long long ks[8];
#pragma unroll
    for (int s = 0; s < 8; ++s) {
        int e = (s << 6) + l;
        ks[s] = (e < cbase) ? comp[e] : INFK;
    }
    unsigned keep = 0;
    for (int r = 0; r < 17; ++r) {
        unsigned long long ml = ks[0];
#pragma unroll
        for (int s = 1; s < 8; ++s) ml = (ks[s] < ml) ? ks[s] : ml;
        unsigned long long g = ml;
#pragma unroll
        for (int o = 1; o < 64; o <<= 1) {
            unsigned long long o2 = __shfl_xor(g, o);
            g = (o2 < g) ? o2 : g;
        }
        unsigned long long bal = __ballot(ml == g);
        if (l == (__ffsll((unsigned long long)bal) - 1)) {
            bool done = false;
#pragma unroll
            for (int s = 0; s < 8; ++s)
                if (!done && ks[s] == g) { ks[s] = INFK; done = true; }
        }
        if (l == r - 1) keep = (unsigned)g;
    }
    if (l < 16) out_idx[(size_t)q * 16 + l] = (int)keep;
}

// ---------------------------------------------------------------------------
// Fused v2: 4 waves/block, one point per wave, zero barriers (wave-private
// LDS). All GEMMs via mfma_f32_16x16x32_bf16, M=16 = the K neighbors.
// y channel layout: [mid 0..31 | h2 32..63 | x 64..127].
// ---------------------------------------------------------------------------
__global__ __launch_bounds__(256)
void fused2_kernel(const float* __restrict__ x, const int* __restrict__ knn,
                   const short* __restrict__ W1T, const short* __restrict__ W2T,
                   const short* __restrict__ WmidT, const short* __restrict__ WlastT,
                   const float* __restrict__ b1, const float* __restrict__ b2,
                   const float* __restrict__ bmid,
                   const float* __restrict__ Wg, const float* __restrict__ bg,
                   const float* __restrict__ blast,
                   float* __restrict__ out) {
    __shared__ short s_edge[4][16 * 200];   // [k][200] pad
    __shared__ short s_chunk[4][16 * 40];   // h1 32-col chunk, [k][40] pad
    __shared__ short s_y[4][16 * 136];      // [k][136] pad
    __shared__ float s_ym[4][128];

    const int w = threadIdx.x >> 6;
    const int l = threadIdx.x & 63;
    const int p = blockIdx.x * 4 + w;
    const int b = p >> 12;
    short* se = s_edge[w];
    short* sc = s_chunk[w];
    short* sy = s_y[w];

    const int c16 = l & 15;   // A-row / output col within tile
    const int qa = l >> 4;    // k-quadrant

    // ---- edge staging ----
    const float xi = x[(size_t)p * 64 + l];
    const short xib = f2b(xi);
    const int nbv = knn[(size_t)p * 16 + c16];
#pragma unroll 4
    for (int k = 0; k < 16; ++k) {
        int nb = __shfl(nbv, k);
        float xn = x[((size_t)(b << 12) + nb) * 64 + l];
        se[k * 200 + l] = xib;
        se[k * 200 + 64 + l] = f2b(xn);
        se[k * 200 + 128 + l] = f2b(xn - xi);
        sy[k * 136 + 64 + l] = xib;
    }

    // ---- h1 (16x256, K=192) fused with h2 (16x32, K=256) ----
    f32x4 hacc[2];
    {
        float h0 = b2[c16], h1b = b2[16 + c16];
        hacc[0] = (f32x4){h0, h0, h0, h0};
        hacc[1] = (f32x4){h1b, h1b, h1b, h1b};
    }
    for (int c2 = 0; c2 < 8; ++c2) {
        const int col0 = c2 * 32 + c16, col1 = col0 + 16;
        float bb0 = b1[col0], bb1 = b1[col1];
        f32x4 a0 = (f32x4){bb0, bb0, bb0, bb0};
        f32x4 a1 = (f32x4){bb1, bb1, bb1, bb1};
#pragma unroll
        for (int t = 0; t < 6; ++t) {
            bf16x8 av = *(const bf16x8*)(se + c16 * 200 + t * 32 + qa * 8);
            bf16x8 bv0 = *(const bf16x8*)(W1T + (size_t)col0 * 192 + t * 32 + qa * 8);
            bf16x8 bv1 = *(const bf16x8*)(W1T + (size_t)col1 * 192 + t * 32 + qa * 8);
            a0 = MFMA16(av, bv0, a0);
            a1 = MFMA16(av, bv1, a1);
        }
#pragma unroll
        for (int r = 0; r < 4; ++r) {
            int row = qa * 4 + r;
            sc[row * 40 + c16] = f2b(fmaxf(a0[r], 0.f));
            sc[row * 40 + 16 + c16] = f2b(fmaxf(a1[r], 0.f));
        }
        bf16x8 a2 = *(const bf16x8*)(sc + c16 * 40 + qa * 8);
        bf16x8 w20 = *(const bf16x8*)(W2T + (size_t)c16 * 256 + c2 * 32 + qa * 8);
        bf16x8 w21 = *(const bf16x8*)(W2T + (size_t)(16 + c16) * 256 + c2 * 32 + qa * 8);
        hacc[0] = MFMA16(a2, w20, hacc[0]);
        hacc[1] = MFMA16(a2, w21, hacc[1]);
    }
#pragma unroll
    for (int nt = 0; nt < 2; ++nt)
#pragma unroll
        for (int r = 0; r < 4; ++r) {
            int row = qa * 4 + r;
            sy[row * 136 + 32 + nt * 16 + c16] = f2b(fmaxf(hacc[nt][r], 0.f));
        }

    // ---- mid (16x32, K=96 over [h2|x]) ----
    {
        f32x4 macc[2];
        float m0 = bmid[c16], m1 = bmid[16 + c16];
        macc[0] = (f32x4){m0, m0, m0, m0};
        macc[1] = (f32x4){m1, m1, m1, m1};
#pragma unroll
        for (int t = 0; t < 3; ++t) {
            bf16x8 av = *(const bf16x8*)(sy + c16 * 136 + 32 + t * 32 + qa * 8);
            bf16x8 b0v = *(const bf16x8*)(WmidT + (size_t)c16 * 96 + t * 32 + qa * 8);
            bf16x8 b1v = *(const bf16x8*)(WmidT + (size_t)(16 + c16) * 96 + t * 32 + qa * 8);
            macc[0] = MFMA16(av, b0v, macc[0]);
            macc[1] = MFMA16(av, b1v, macc[1]);
        }
#pragma unroll
        for (int nt = 0; nt < 2; ++nt)
#pragma unroll
            for (int r = 0; r < 4; ++r) {
                int row = qa * 4 + r;
                sy[row * 136 + nt * 16 + c16] = f2b(fmaxf(macc[nt][r], 0.f));
            }
    }

    // ---- mean over k ----
    {
        float s0 = 0.f, s1 = 0.f;
#pragma unroll
        for (int k = 0; k < 16; ++k) {
            s0 += b2f(sy[k * 136 + l]);
            s1 += b2f(sy[k * 136 + 64 + l]);
        }
        s_ym[w][l] = s0 * 0.0625f;
        s_ym[w][64 + l] = s1 * 0.0625f;
    }

    // ---- gate (sigmoid(ym @ Wg + bg)), 2 channels per lane, kept in regs ----
    float g0, g1;
    {
        const int c0 = 2 * l;
        float a0 = bg[c0], a1 = bg[c0 + 1];
        for (int r = 0; r < 128; ++r) {
            float ym = s_ym[w][r];
            float2 wg = *(const float2*)(Wg + (size_t)r * 128 + c0);
            a0 = __fmaf_rn(ym, wg.x, a0);
            a1 = __fmaf_rn(ym, wg.y, a1);
        }
        g0 = 1.f / (1.f + __expf(-a0));
        g1 = 1.f / (1.f + __expf(-a1));
    }

    // ---- y *= gate (in-place bf16), fused y-part max + store ----
    {
        const int c0 = 2 * l;
        float m0 = -__uint_as_float(0x7F800000u), m1 = m0;
#pragma unroll
        for (int k = 0; k < 16; ++k) {
            unsigned pk = *(const unsigned*)(sy + k * 136 + c0);
            float v0 = b2f((short)(pk & 0xFFFFu)) * g0;
            float v1 = b2f((short)(pk >> 16)) * g1;
            m0 = fmaxf(m0, v0);
            m1 = fmaxf(m1, v1);
            unsigned np = ((unsigned)(unsigned short)f2b(v1) << 16) |
                          (unsigned)(unsigned short)f2b(v0);
            *(unsigned*)(sy + k * 136 + c0) = np;
        }
        float2 st; st.x = m0; st.y = m1;
        *(float2*)(out + (size_t)p * 160 + 32 + c0) = st;
    }

    // ---- z = y_gated @ Wlast + blast (16x32, K=128), fused max + store ----
    {
        f32x4 zacc[2];
        float z0 = blast[c16], z1 = blast[16 + c16];
        zacc[0] = (f32x4){z0, z0, z0, z0};
        zacc[1] = (f32x4){z1, z1, z1, z1};
#pragma unroll
        for (int t = 0; t < 4; ++t) {
            bf16x8 av = *(const bf16x8*)(sy + c16 * 136 + t * 32 + qa * 8);
            bf16x8 b0v = *(const bf16x8*)(WlastT + (size_t)c16 * 128 + t * 32 + qa * 8);
            bf16x8 b1v = *(const bf16x8*)(WlastT + (size_t)(16 + c16) * 128 + t * 32 + qa * 8);
            zacc[0] = MFMA16(av, b0v, zacc[0]);
            zacc[1] = MFMA16(av, b1v, zacc[1]);
        }
#pragma unroll
        for (int nt = 0; nt < 2; ++nt) {
            float m = fmaxf(fmaxf(zacc[nt][0], zacc[nt][1]),
                            fmaxf(zacc[nt][2], zacc[nt][3]));
            m = fmaxf(m, __shfl_xor(m, 16));
            m = fmaxf(m, __shfl_xor(m, 32));
            if (l < 16) out[(size_t)p * 160 + nt * 16 + l] = m;
        }
    }
}

extern "C" void kernel_launch(void* const* d_in, const int* in_sizes, int n_in,
                              void* d_out, int out_size, void* d_ws, size_t ws_size,
                              hipStream_t stream) {
    const float* x     = (const float*)d_in[0];
    const float* pos   = (const float*)d_in[1];
    const float* W1    = (const float*)d_in[2];
    const float* b1    = (const float*)d_in[3];
    const float* W2    = (const float*)d_in[4];
    const float* b2    = (const float*)d_in[5];
    const float* Wmid  = (const float*)d_in[6];
    const float* bmid  = (const float*)d_in[7];
    const float* Wg    = (const float*)d_in[8];
    const float* bg    = (const float*)d_in[9];
    const float* Wlast = (const float*)d_in[10];
    const float* blast = (const float*)d_in[11];
    float* out = (float*)d_out;

    char* ws = (char*)d_ws;
    int*   idx   = (int*)(ws + 0);              // 2,097,152 B
    float* px    = (float*)(ws + 2097152);      // 131,072 B
    float* py    = (float*)(ws + 2228224);
    float* pz    = (float*)(ws + 2359296);
    float* sq    = (float*)(ws + 2490368);
    short* W1T   = (short*)(ws + 2621440);      // 98,304 B
    short* W2T   = (short*)(ws + 2719744);      // 16,384 B
    short* WmidT = (short*)(ws + 2736128);      // 6,144 B
    short* WlastT= (short*)(ws + 2742272);      // 8,192 B

    prep_kernel<<<dim3(380), dim3(256), 0, stream>>>(
        pos, W1, W2, Wmid, Wlast, px, py, pz, sq, W1T, W2T, WmidT, WlastT);
    knn2_kernel<<<dim3(BB * NN), dim3(64), 0, stream>>>(px, py, pz, sq, idx);
    fused2_kernel<<<dim3(BB * NN / 4), dim3(256), 0, stream>>>(
        x, idx, W1T, W2T, WmidT, WlastT, b1, b2, bmid, Wg, bg, blast, out);
}

// Round 6
// 757.827 us; speedup vs baseline: 3.5277x; 1.4125x over previous
//
#include <hip/hip_runtime.h>
#include <stdint.h>

#define BB 8
#define NN 4096

typedef float f32x4 __attribute__((ext_vector_type(4)));
typedef short bf16x8 __attribute__((ext_vector_type(8)));
// may_alias variants: ALL type-punned LDS traffic goes through these, so the
// compiler can never reorder ds_read/ds_write pairs of "different" types.
typedef bf16x8 bf16x8a __attribute__((may_alias));
typedef unsigned u32a __attribute__((may_alias));
#define MFMA16(a, b, c) __builtin_amdgcn_mfma_f32_16x16x32_bf16(a, b, c, 0, 0, 0)

static __device__ __forceinline__ short f2b(float f) {
    unsigned u = __float_as_uint(f);
    unsigned r = (u + 0x7FFFu + ((u >> 16) & 1u)) >> 16;   // RNE, finite values
    return (short)r;
}
static __device__ __forceinline__ float b2f(short s) {
    return __uint_as_float(((unsigned)(unsigned short)s) << 16);
}
static __device__ __forceinline__ bf16x8 pack8(float4 a, float4 b) {
    bf16x8 v;
    v[0] = f2b(a.x); v[1] = f2b(a.y); v[2] = f2b(a.z); v[3] = f2b(a.w);
    v[4] = f2b(b.x); v[5] = f2b(b.y); v[6] = f2b(b.z); v[7] = f2b(b.w);
    return v;
}

// ---------------------------------------------------------------------------
// Prep: pq = (x,y,z,sq) packed (exact reference arithmetic for sq);
// weights -> bf16 transposed [col][k] for contiguous MFMA B-fragments.
// ---------------------------------------------------------------------------
__global__ __launch_bounds__(256)
void prep_kernel(const float* __restrict__ pos,
                 const float* __restrict__ W1, const float* __restrict__ W2,
                 const float* __restrict__ Wmid, const float* __restrict__ Wlast,
                 const float* __restrict__ Wg,
                 float4* __restrict__ pq,
                 short* __restrict__ W1T, short* __restrict__ W2T,
                 short* __restrict__ WmidT, short* __restrict__ WlastT,
                 short* __restrict__ WgT) {
    int t = blockIdx.x * 256 + threadIdx.x;
    if (t < 32768) {
        float x = pos[t * 3 + 0], y = pos[t * 3 + 1], z = pos[t * 3 + 2];
        float s = __fadd_rn(__fadd_rn(__fmul_rn(x, x), __fmul_rn(y, y)), __fmul_rn(z, z));
        pq[t] = make_float4(x, y, z, s);
    } else if (t < 81920) {          // W1T[col*192+k], col<256,k<192
        int e = t - 32768; int col = e / 192, k = e - col * 192;
        W1T[e] = f2b(W1[(size_t)k * 256 + col]);
    } else if (t < 90112) {          // W2T[col*256+k]
        int e = t - 81920; int col = e >> 8, k = e & 255;
        W2T[e] = f2b(W2[(size_t)k * 32 + col]);
    } else if (t < 93184) {          // WmidT[col*96+k]
        int e = t - 90112; int col = e / 96, k = e - col * 96;
        WmidT[e] = f2b(Wmid[(size_t)k * 32 + col]);
    } else if (t < 97280) {          // WlastT[col*128+k]
        int e = t - 93184; int col = e >> 7, k = e & 127;
        WlastT[e] = f2b(Wlast[(size_t)k * 32 + col]);
    } else if (t < 113664) {         // WgT[col*128+k]
        int e = t - 97280; int col = e >> 7, k = e & 127;
        WgT[e] = f2b(Wg[(size_t)k * 128 + col]);
    }
}

// ---------------------------------------------------------------------------
// KNN v2 — the ROUND-2 PASSING kernel (pq-packed reads). One wave per query;
// dists cached in LDS; butterfly tau; compact; 17x stable extract-min.
// All LDS accesses type-consistent (float / u64): no puns here.
// ---------------------------------------------------------------------------
__global__ __launch_bounds__(64)
void knn2_kernel(const float4* __restrict__ pq, int* __restrict__ out_idx) {
    __shared__ float sd[64 * 65];
    __shared__ unsigned long long comp[512];

    const int q = blockIdx.x;
    const int b = q >> 12, i = q & 4095;
    const int l = threadIdx.x;
    const int base = b << 12;
    const float INF = __uint_as_float(0x7F800000u);

    const float4 self = pq[base + i];
    const float qx = self.x, qy = self.y, qz = self.z, qsq = self.w;

    float lmin = INF;
#pragma unroll 4
    for (int t = 0; t < 64; ++t) {
        int j = (t << 6) + l;
        float4 v = pq[base + j];
        float dot = __fmaf_rn(v.z, qz, __fmaf_rn(v.y, qy, __fmul_rn(v.x, qx)));
        float d = __fsub_rn(__fadd_rn(qsq, v.w), __fmul_rn(2.0f, dot));
        d = fmaxf(d, 0.0f);
        sd[l * 65 + t] = d;
        lmin = fminf(lmin, d);
    }

    // B) 17th smallest of lane minima
    float cur = lmin, tau = INF;
    for (int r = 0; r < 17; ++r) {
        float m = cur;
#pragma unroll
        for (int o = 1; o < 64; o <<= 1) m = fminf(m, __shfl_xor(m, o));
        unsigned long long bal = __ballot(cur == m);
        if (l == (__ffsll((unsigned long long)bal) - 1)) cur = INF;
        tau = m;
    }

    // C) compact
    int cbase = 0;
    const unsigned long long ltm = (l == 0) ? 0ull : ((~0ull) >> (64 - l));
    for (int t = 0; t < 64; ++t) {
        float d = sd[l * 65 + t];
        bool pr = (d <= tau);
        unsigned long long bal = __ballot(pr);
        if (pr) {
            int ps = cbase + __popcll(bal & ltm);
            if (ps < 512)
                comp[ps] = ((unsigned long long)__float_as_uint(d) << 32) |
                           (unsigned)((t << 6) + l);
        }
        cbase += __popcll(bal);
    }
    if (cbase > 512) cbase = 512;

    // D) extract stable top-17
    const unsigned long long INFK = ~0ull;
    unsigned long long ks[8];
#pragma unroll
    for (int s = 0; s < 8; ++s) {
        int e = (s << 6) + l;
        ks[s] = (e < cbase) ? comp[e] : INFK;
    }
    unsigned keep = 0;
    for (int r = 0; r < 17; ++r) {
        unsigned long long ml = ks[0];
#pragma unroll
        for (int s = 1; s < 8; ++s) ml = (ks[s] < ml) ? ks[s] : ml;
        unsigned long long g = ml;
#pragma unroll
        for (int o = 1; o < 64; o <<= 1) {
            unsigned long long o2 = __shfl_xor(g, o);
            g = (o2 < g) ? o2 : g;
        }
        unsigned long long bal = __ballot(ml == g);
        if (l == (__ffsll((unsigned long long)bal) - 1)) {
            bool done = false;
#pragma unroll
            for (int s = 0; s < 8; ++s)
                if (!done && ks[s] == g) { ks[s] = INFK; done = true; }
        }
        if (l == r - 1) keep = (unsigned)g;
    }
    if (l < 16) out_idx[(size_t)q * 16 + l] = (int)keep;
}

// ---------------------------------------------------------------------------
// Fused v5 = fused4 with the alias/ordering bugfix bundle:
//  - NO unsigned puns: phases 4/6 use short loads/stores matching the writes
//  - all vector LDS accesses via may_alias bf16x8a
//  - extra __syncthreads() between phases 3->4 and 6->7
//  - neighbor index clamped to [0,4095]
// Structure: block = 4 waves = 4 points; h1 column-split across waves;
// h2/mid/ym per-point. y layout: [mid 0..31 | h2 32..63 | x 64..127].
// ---------------------------------------------------------------------------
__global__ __launch_bounds__(256, 3)
void fused5_kernel(const float* __restrict__ x, const int* __restrict__ knn,
                   const short* __restrict__ W1T, const short* __restrict__ W2T,
                   const short* __restrict__ WmidT, const short* __restrict__ WlastT,
                   const short* __restrict__ WgT,
                   const float* __restrict__ b1, const float* __restrict__ b2,
                   const float* __restrict__ bmid, const float* __restrict__ bg,
                   const float* __restrict__ blast,
                   float* __restrict__ out) {
    __shared__ __align__(16) short s_h[64 * 264];   // edge[64][<=224] then h1[64][256]
    __shared__ __align__(16) short s_y[64 * 136];
    __shared__ __align__(16) short s_ym[4 * 128];   // bf16 means, row = point
    __shared__ float s_gate[4][128];

    const int w = threadIdx.x >> 6;
    const int l = threadIdx.x & 63;
    const int c16 = l & 15;
    const int qa = l >> 4;
    const int p = blockIdx.x * 4 + w;
    const int b = p >> 12;

    // ---- phase 0: edge staging (row = w*16+c16; feature chunks qa*8, 32+qa*8)
    {
        const float* xrow = x + (size_t)p * 64;
        float4 xa = *(const float4*)(xrow + qa * 8);
        float4 xb = *(const float4*)(xrow + qa * 8 + 4);
        float4 xc = *(const float4*)(xrow + 32 + qa * 8);
        float4 xd = *(const float4*)(xrow + 32 + qa * 8 + 4);
        int nb = knn[(size_t)p * 16 + c16] & 4095;   // clamp: no wild reads ever
        const float* nrow = x + ((size_t)(b << 12) + nb) * 64;
        float4 na = *(const float4*)(nrow + qa * 8);
        float4 nb4 = *(const float4*)(nrow + qa * 8 + 4);
        float4 nc = *(const float4*)(nrow + 32 + qa * 8);
        float4 nd = *(const float4*)(nrow + 32 + qa * 8 + 4);
        float4 da, db, dc, dd;
        da.x = na.x - xa.x; da.y = na.y - xa.y; da.z = na.z - xa.z; da.w = na.w - xa.w;
        db.x = nb4.x - xb.x; db.y = nb4.y - xb.y; db.z = nb4.z - xb.z; db.w = nb4.w - xb.w;
        dc.x = nc.x - xc.x; dc.y = nc.y - xc.y; dc.z = nc.z - xc.z; dc.w = nc.w - xc.w;
        dd.x = nd.x - xd.x; dd.y = nd.y - xd.y; dd.z = nd.z - xd.z; dd.w = nd.w - xd.w;
        bf16x8 pxa = pack8(xa, xb), pxc = pack8(xc, xd);
        int row = w * 16 + c16;
        short* sr = s_h + row * 264;
        *(bf16x8a*)(sr + qa * 8)       = pxa;
        *(bf16x8a*)(sr + 32 + qa * 8)  = pxc;
        *(bf16x8a*)(sr + 64 + qa * 8)  = pack8(na, nb4);
        *(bf16x8a*)(sr + 96 + qa * 8)  = pack8(nc, nd);
        *(bf16x8a*)(sr + 128 + qa * 8) = pack8(da, db);
        *(bf16x8a*)(sr + 160 + qa * 8) = pack8(dc, dd);
        short* yr = s_y + row * 136;
        *(bf16x8a*)(yr + 64 + qa * 8)  = pxa;
        *(bf16x8a*)(yr + 96 + qa * 8)  = pxc;
    }
    __syncthreads();                                // B1: edge ready

    // ---- phase 1a: h1 MFMA — wave w owns cols [w*64, w*64+64); 16 chains
    f32x4 acc[4][4];
#pragma unroll
    for (int n = 0; n < 4; ++n) {
        float bv = b1[w * 64 + n * 16 + c16];
#pragma unroll
        for (int m = 0; m < 4; ++m) acc[m][n] = (f32x4){bv, bv, bv, bv};
    }
    {
        const short* w1p = W1T + (size_t)(w * 64 + c16) * 192 + qa * 8;
#pragma unroll
        for (int t = 0; t < 6; ++t) {
            bf16x8 av[4], bw[4];
#pragma unroll
            for (int m = 0; m < 4; ++m)
                av[m] = *(const bf16x8a*)(s_h + (m * 16 + c16) * 264 + t * 32 + qa * 8);
#pragma unroll
            for (int n = 0; n < 4; ++n)
                bw[n] = *(const bf16x8a*)(w1p + (size_t)n * 3072 + t * 32);
#pragma unroll
            for (int m = 0; m < 4; ++m)
#pragma unroll
                for (int n = 0; n < 4; ++n)
                    acc[m][n] = MFMA16(av[m], bw[n], acc[m][n]);
        }
    }
    __syncthreads();                                // B2: all edge reads done

    // ---- phase 1b: write h1 (bf16) into s_h, cols w*64..w*64+64, all rows
#pragma unroll
    for (int m = 0; m < 4; ++m)
#pragma unroll
        for (int n = 0; n < 4; ++n)
#pragma unroll
            for (int r = 0; r < 4; ++r)
                s_h[(m * 16 + qa * 4 + r) * 264 + w * 64 + n * 16 + c16] =
                    f2b(fmaxf(acc[m][n][r], 0.f));
    __syncthreads();                                // B3: full h1 ready

    // ---- phase 2: h2 per-point (rows w*16.., K=256) -> s_y cols 32..63
    {
        f32x4 hacc[2];
        float h0 = b2[c16], h1v = b2[16 + c16];
        hacc[0] = (f32x4){h0, h0, h0, h0};
        hacc[1] = (f32x4){h1v, h1v, h1v, h1v};
#pragma unroll
        for (int t = 0; t < 8; ++t) {
            bf16x8 am = *(const bf16x8a*)(s_h + (w * 16 + c16) * 264 + t * 32 + qa * 8);
            bf16x8 wb0 = *(const bf16x8a*)(W2T + (size_t)c16 * 256 + t * 32 + qa * 8);
            bf16x8 wb1 = *(const bf16x8a*)(W2T + (size_t)(16 + c16) * 256 + t * 32 + qa * 8);
            hacc[0] = MFMA16(am, wb0, hacc[0]);
            hacc[1] = MFMA16(am, wb1, hacc[1]);
        }
#pragma unroll
        for (int n2 = 0; n2 < 2; ++n2)
#pragma unroll
            for (int r = 0; r < 4; ++r)
                s_y[(w * 16 + qa * 4 + r) * 136 + 32 + n2 * 16 + c16] =
                    f2b(fmaxf(hacc[n2][r], 0.f));
    }

    // ---- phase 3: mid (own point, K=96 over [h2|x]) -> s_y cols 0..31
    {
        f32x4 macc[2];
        float m0 = bmid[c16], m1 = bmid[16 + c16];
        macc[0] = (f32x4){m0, m0, m0, m0};
        macc[1] = (f32x4){m1, m1, m1, m1};
#pragma unroll
        for (int t = 0; t < 3; ++t) {
            bf16x8 av = *(const bf16x8a*)(s_y + (w * 16 + c16) * 136 + 32 + t * 32 + qa * 8);
            bf16x8 wb0 = *(const bf16x8a*)(WmidT + (size_t)c16 * 96 + t * 32 + qa * 8);
            bf16x8 wb1 = *(const bf16x8a*)(WmidT + (size_t)(16 + c16) * 96 + t * 32 + qa * 8);
            macc[0] = MFMA16(av, wb0, macc[0]);
            macc[1] = MFMA16(av, wb1, macc[1]);
        }
#pragma unroll
        for (int n2 = 0; n2 < 2; ++n2)
#pragma unroll
            for (int r = 0; r < 4; ++r)
                s_y[(w * 16 + qa * 4 + r) * 136 + n2 * 16 + c16] =
                    f2b(fmaxf(macc[n2][r], 0.f));
    }
    __syncthreads();                                // B3b: mid fully written

    // ---- phase 4: ym = mean over k (own point) — SHORT loads/stores only
    {
        float s0 = 0.f, s1 = 0.f;
#pragma unroll
        for (int k = 0; k < 16; ++k) {
            const short* yp = s_y + (w * 16 + k) * 136;
            s0 += b2f(yp[2 * l]);
            s1 += b2f(yp[2 * l + 1]);
        }
        s_ym[w * 128 + 2 * l]     = f2b(s0 * 0.0625f);
        s_ym[w * 128 + 2 * l + 1] = f2b(s1 * 0.0625f);
    }
    __syncthreads();                                // B4: all 4 points' ym ready

    // ---- phase 5: gate — one M-tile (rows = points), wave w owns cols w*32..
    {
        f32x4 gacc[2];
        float g0 = bg[w * 32 + c16], g1 = bg[w * 32 + 16 + c16];
        gacc[0] = (f32x4){g0, g0, g0, g0};
        gacc[1] = (f32x4){g1, g1, g1, g1};
#pragma unroll
        for (int t = 0; t < 4; ++t) {
            bf16x8 av = *(const bf16x8a*)(s_ym + (c16 & 3) * 128 + t * 32 + qa * 8);
            bf16x8 wb0 = *(const bf16x8a*)(WgT + (size_t)(w * 32 + c16) * 128 + t * 32 + qa * 8);
            bf16x8 wb1 = *(const bf16x8a*)(WgT + (size_t)(w * 32 + 16 + c16) * 128 + t * 32 + qa * 8);
            gacc[0] = MFMA16(av, wb0, gacc[0]);
            gacc[1] = MFMA16(av, wb1, gacc[1]);
        }
        if (qa == 0) {
#pragma unroll
            for (int n2 = 0; n2 < 2; ++n2)
#pragma unroll
                for (int r = 0; r < 4; ++r)
                    s_gate[r][w * 32 + n2 * 16 + c16] =
                        1.0f / (1.0f + __expf(-gacc[n2][r]));
        }
    }
    __syncthreads();                                // B5: gates ready

    // ---- phase 6: y *= gate (in place, SHORT ops), fused y-max + store
    {
        float g0 = s_gate[w][2 * l], g1 = s_gate[w][2 * l + 1];
        float m0 = -__uint_as_float(0x7F800000u), m1 = m0;
#pragma unroll
        for (int k = 0; k < 16; ++k) {
            short* yp = s_y + (w * 16 + k) * 136;
            float v0 = b2f(yp[2 * l]) * g0;
            float v1 = b2f(yp[2 * l + 1]) * g1;
            m0 = fmaxf(m0, v0);
            m1 = fmaxf(m1, v1);
            yp[2 * l]     = f2b(v0);
            yp[2 * l + 1] = f2b(v1);
        }
        float2 st; st.x = m0; st.y = m1;
        *(float2*)(out + (size_t)p * 160 + 32 + 2 * l) = st;
    }
    __syncthreads();                                // B6: gated y fully written

    // ---- phase 7: z = y_gated @ Wlast + blast; max over k; store ch 0..31
    {
        f32x4 zacc[2];
        float z0 = blast[c16], z1 = blast[16 + c16];
        zacc[0] = (f32x4){z0, z0, z0, z0};
        zacc[1] = (f32x4){z1, z1, z1, z1};
#pragma unroll
        for (int t = 0; t < 4; ++t) {
            bf16x8 av = *(const bf16x8a*)(s_y + (w * 16 + c16) * 136 + t * 32 + qa * 8);
            bf16x8 wb0 = *(const bf16x8a*)(WlastT + (size_t)c16 * 128 + t * 32 + qa * 8);
            bf16x8 wb1 = *(const bf16x8a*)(WlastT + (size_t)(16 + c16) * 128 + t * 32 + qa * 8);
            zacc[0] = MFMA16(av, wb0, zacc[0]);
            zacc[1] = MFMA16(av, wb1, zacc[1]);
        }
#pragma unroll
        for (int nt = 0; nt < 2; ++nt) {
            float m = fmaxf(fmaxf(zacc[nt][0], zacc[nt][1]),
                            fmaxf(zacc[nt][2], zacc[nt][3]));
            m = fmaxf(m, __shfl_xor(m, 16));
            m = fmaxf(m, __shfl_xor(m, 32));
            if (l < 16) out[(size_t)p * 160 + nt * 16 + l] = m;
        }
    }
}

extern "C" void kernel_launch(void* const* d_in, const int* in_sizes, int n_in,
                              void* d_out, int out_size, void* d_ws, size_t ws_size,
                              hipStream_t stream) {
    const float* x     = (const float*)d_in[0];
    const float* pos   = (const float*)d_in[1];
    const float* W1    = (const float*)d_in[2];
    const float* b1    = (const float*)d_in[3];
    const float* W2    = (const float*)d_in[4];
    const float* b2    = (const float*)d_in[5];
    const float* Wmid  = (const float*)d_in[6];
    const float* bmid  = (const float*)d_in[7];
    const float* Wg    = (const float*)d_in[8];
    const float* bg    = (const float*)d_in[9];
    const float* Wlast = (const float*)d_in[10];
    const float* blast = (const float*)d_in[11];
    float* out = (float*)d_out;

    char* ws = (char*)d_ws;
    int*    idx    = (int*)(ws + 0);              // 2,097,152 B
    float4* pq     = (float4*)(ws + 2097152);     // 524,288 B
    short*  W1T    = (short*)(ws + 2621440);      // 98,304 B
    short*  W2T    = (short*)(ws + 2719744);      // 16,384 B
    short*  WmidT  = (short*)(ws + 2736128);      // 6,144 B
    short*  WlastT = (short*)(ws + 2742272);      // 8,192 B
    short*  WgT    = (short*)(ws + 2750464);      // 32,768 B

    prep_kernel<<<dim3(444), dim3(256), 0, stream>>>(
        pos, W1, W2, Wmid, Wlast, Wg, pq, W1T, W2T, WmidT, WlastT, WgT);
    knn2_kernel<<<dim3(BB * NN), dim3(64), 0, stream>>>(pq, idx);
    fused5_kernel<<<dim3(BB * NN / 4), dim3(256), 0, stream>>>(
        x, idx, W1T, W2T, WmidT, WlastT, WgT, b1, b2, bmid, bg, blast, out);
}

// Round 7
// 507.366 us; speedup vs baseline: 5.2692x; 1.4936x over previous
//
#include <hip/hip_runtime.h>
#include <stdint.h>

#define BB 8
#define NN 4096

typedef float f32x4 __attribute__((ext_vector_type(4)));
typedef short bf16x8 __attribute__((ext_vector_type(8)));
// may_alias variants: ALL type-punned LDS traffic goes through these, so the
// compiler can never reorder ds_read/ds_write pairs of "different" types.
typedef bf16x8 bf16x8a __attribute__((may_alias));
#define MFMA16(a, b, c) __builtin_amdgcn_mfma_f32_16x16x32_bf16(a, b, c, 0, 0, 0)

static __device__ __forceinline__ short f2b(float f) {
    unsigned u = __float_as_uint(f);
    unsigned r = (u + 0x7FFFu + ((u >> 16) & 1u)) >> 16;   // RNE, finite values
    return (short)r;
}
static __device__ __forceinline__ float b2f(short s) {
    return __uint_as_float(((unsigned)(unsigned short)s) << 16);
}
static __device__ __forceinline__ bf16x8 pack8(float4 a, float4 b) {
    bf16x8 v;
    v[0] = f2b(a.x); v[1] = f2b(a.y); v[2] = f2b(a.z); v[3] = f2b(a.w);
    v[4] = f2b(b.x); v[5] = f2b(b.y); v[6] = f2b(b.z); v[7] = f2b(b.w);
    return v;
}

// ---------------------------------------------------------------------------
// Prep: pq = (x,y,z,sq) packed (exact reference arithmetic for sq);
// weights -> bf16 transposed [col][k] for contiguous MFMA B-fragments.
// ---------------------------------------------------------------------------
__global__ __launch_bounds__(256)
void prep_kernel(const float* __restrict__ pos,
                 const float* __restrict__ W1, const float* __restrict__ W2,
                 const float* __restrict__ Wmid, const float* __restrict__ Wlast,
                 const float* __restrict__ Wg,
                 float4* __restrict__ pq,
                 short* __restrict__ W1T, short* __restrict__ W2T,
                 short* __restrict__ WmidT, short* __restrict__ WlastT,
                 short* __restrict__ WgT) {
    int t = blockIdx.x * 256 + threadIdx.x;
    if (t < 32768) {
        float x = pos[t * 3 + 0], y = pos[t * 3 + 1], z = pos[t * 3 + 2];
        float s = __fadd_rn(__fadd_rn(__fmul_rn(x, x), __fmul_rn(y, y)), __fmul_rn(z, z));
        pq[t] = make_float4(x, y, z, s);
    } else if (t < 81920) {          // W1T[col*192+k], col<256,k<192
        int e = t - 32768; int col = e / 192, k = e - col * 192;
        W1T[e] = f2b(W1[(size_t)k * 256 + col]);
    } else if (t < 90112) {          // W2T[col*256+k]
        int e = t - 81920; int col = e >> 8, k = e & 255;
        W2T[e] = f2b(W2[(size_t)k * 32 + col]);
    } else if (t < 93184) {          // WmidT[col*96+k]
        int e = t - 90112; int col = e / 96, k = e - col * 96;
        WmidT[e] = f2b(Wmid[(size_t)k * 32 + col]);
    } else if (t < 97280) {          // WlastT[col*128+k]
        int e = t - 93184; int col = e >> 7, k = e & 127;
        WlastT[e] = f2b(Wlast[(size_t)k * 32 + col]);
    } else if (t < 113664) {         // WgT[col*128+k]
        int e = t - 97280; int col = e >> 7, k = e & 127;
        WgT[e] = f2b(Wg[(size_t)k * 128 + col]);
    }
}

static __device__ __forceinline__ float distf(float4 v, float qx, float qy,
                                              float qz, float qsq) {
    float dot = __fmaf_rn(v.z, qz, __fmaf_rn(v.y, qy, __fmul_rn(v.x, qx)));
    float d = __fsub_rn(__fadd_rn(qsq, v.w), __fmul_rn(2.0f, dot));
    return fmaxf(d, 0.0f);
}

// ---------------------------------------------------------------------------
// KNN v4: same algorithm as the PASSING knn2 (butterfly tau + ballot-compact
// + 17x stable extract-min of (dist_bits<<32|idx), bit-identical distance
// arithmetic), with two occupancy deltas: distances recomputed instead of
// LDS-cached (21KB -> 5KB), and 4 waves per block.
// ---------------------------------------------------------------------------
__global__ __launch_bounds__(256)
void knn4_kernel(const float4* __restrict__ pq, int* __restrict__ out_idx) {
    __shared__ unsigned long long comp[4][160];

    const int w = threadIdx.x >> 6;
    const int l = threadIdx.x & 63;
    const int q = blockIdx.x * 4 + w;
    const int b = q >> 12, i = q & 4095;
    const int base = b << 12;
    const float INF = __uint_as_float(0x7F800000u);

    const float4 self = pq[base + i];
    const float qx = self.x, qy = self.y, qz = self.z, qsq = self.w;

    // A) lane minima (lane l covers j = t*64 + l)
    float lmin = INF;
#pragma unroll 4
    for (int t = 0; t < 64; ++t)
        lmin = fminf(lmin, distf(pq[base + t * 64 + l], qx, qy, qz, qsq));

    // B) tau = 17th-smallest lane-min (knn2's butterfly + knockout)
    float cur = lmin, tau = INF;
    for (int r = 0; r < 17; ++r) {
        float m = cur;
#pragma unroll
        for (int o = 1; o < 64; o <<= 1) m = fminf(m, __shfl_xor(m, o));
        unsigned long long bal = __ballot(cur == m);
        if (l == (__ffsll((unsigned long long)bal) - 1)) cur = INF;
        tau = m;
    }

    // C) recompute + ballot-compact survivors (d <= tau guarantees the true
    //    top-17 all survive; identical distance arithmetic to pass A)
    int cbase = 0;
    const unsigned long long ltm = (l == 0) ? 0ull : ((~0ull) >> (64 - l));
    for (int t = 0; t < 64; ++t) {
        float d = distf(pq[base + t * 64 + l], qx, qy, qz, qsq);
        bool pr = (d <= tau);
        unsigned long long bb = __ballot(pr);
        if (pr) {
            int ps = cbase + __popcll(bb & ltm);
            if (ps < 160)
                comp[w][ps] = ((unsigned long long)__float_as_uint(d) << 32) |
                              (unsigned)(t * 64 + l);
        }
        cbase += __popcll(bb);
    }
    if (cbase > 160) cbase = 160;

    // D) knn2's 17x stable extract-min (rank 0 = self, skipped)
    const unsigned long long INFK = ~0ull;
    unsigned long long ks[3];
#pragma unroll
    for (int s = 0; s < 3; ++s) {
        int e = s * 64 + l;
        ks[s] = (e < cbase) ? comp[w][e] : INFK;
    }
    unsigned keep = 0;
    for (int r = 0; r < 17; ++r) {
        unsigned long long ml = ks[0];
#pragma unroll
        for (int s = 1; s < 3; ++s) ml = (ks[s] < ml) ? ks[s] : ml;
        unsigned long long g = ml;
#pragma unroll
        for (int o = 1; o < 64; o <<= 1) {
            unsigned long long o2 = __shfl_xor(g, o);
            g = (o2 < g) ? o2 : g;
        }
        unsigned long long bb = __ballot(ml == g);
        if (l == (__ffsll(bb) - 1)) {
            bool done = false;
#pragma unroll
            for (int s = 0; s < 3; ++s)
                if (!done && ks[s] == g) { ks[s] = INFK; done = true; }
        }
        if (l == r - 1) keep = (unsigned)g;
    }
    if (l < 16) out_idx[(size_t)q * 16 + l] = (int)keep;
}

// ---------------------------------------------------------------------------
// Fused v5 (UNCHANGED from the round-6 passing kernel).
// Structure: block = 4 waves = 4 points; h1 column-split across waves;
// h2/mid/ym per-point. y layout: [mid 0..31 | h2 32..63 | x 64..127].
// ---------------------------------------------------------------------------
__global__ __launch_bounds__(256, 3)
void fused5_kernel(const float* __restrict__ x, const int* __restrict__ knn,
                   const short* __restrict__ W1T, const short* __restrict__ W2T,
                   const short* __restrict__ WmidT, const short* __restrict__ WlastT,
                   const short* __restrict__ WgT,
                   const float* __restrict__ b1, const float* __restrict__ b2,
                   const float* __restrict__ bmid, const float* __restrict__ bg,
                   const float* __restrict__ blast,
                   float* __restrict__ out) {
    __shared__ __align__(16) short s_h[64 * 264];   // edge[64][<=224] then h1[64][256]
    __shared__ __align__(16) short s_y[64 * 136];
    __shared__ __align__(16) short s_ym[4 * 128];   // bf16 means, row = point
    __shared__ float s_gate[4][128];

    const int w = threadIdx.x >> 6;
    const int l = threadIdx.x & 63;
    const int c16 = l & 15;
    const int qa = l >> 4;
    const int p = blockIdx.x * 4 + w;
    const int b = p >> 12;

    // ---- phase 0: edge staging (row = w*16+c16; feature chunks qa*8, 32+qa*8)
    {
        const float* xrow = x + (size_t)p * 64;
        float4 xa = *(const float4*)(xrow + qa * 8);
        float4 xb = *(const float4*)(xrow + qa * 8 + 4);
        float4 xc = *(const float4*)(xrow + 32 + qa * 8);
        float4 xd = *(const float4*)(xrow + 32 + qa * 8 + 4);
        int nb = knn[(size_t)p * 16 + c16] & 4095;   // clamp: no wild reads ever
        const float* nrow = x + ((size_t)(b << 12) + nb) * 64;
        float4 na = *(const float4*)(nrow + qa * 8);
        float4 nb4 = *(const float4*)(nrow + qa * 8 + 4);
        float4 nc = *(const float4*)(nrow + 32 + qa * 8);
        float4 nd = *(const float4*)(nrow + 32 + qa * 8 + 4);
        float4 da, db, dc, dd;
        da.x = na.x - xa.x; da.y = na.y - xa.y; da.z = na.z - xa.z; da.w = na.w - xa.w;
        db.x = nb4.x - xb.x; db.y = nb4.y - xb.y; db.z = nb4.z - xb.z; db.w = nb4.w - xb.w;
        dc.x = nc.x - xc.x; dc.y = nc.y - xc.y; dc.z = nc.z - xc.z; dc.w = nc.w - xc.w;
        dd.x = nd.x - xd.x; dd.y = nd.y - xd.y; dd.z = nd.z - xd.z; dd.w = nd.w - xd.w;
        bf16x8 pxa = pack8(xa, xb), pxc = pack8(xc, xd);
        int row = w * 16 + c16;
        short* sr = s_h + row * 264;
        *(bf16x8a*)(sr + qa * 8)       = pxa;
        *(bf16x8a*)(sr + 32 + qa * 8)  = pxc;
        *(bf16x8a*)(sr + 64 + qa * 8)  = pack8(na, nb4);
        *(bf16x8a*)(sr + 96 + qa * 8)  = pack8(nc, nd);
        *(bf16x8a*)(sr + 128 + qa * 8) = pack8(da, db);
        *(bf16x8a*)(sr + 160 + qa * 8) = pack8(dc, dd);
        short* yr = s_y + row * 136;
        *(bf16x8a*)(yr + 64 + qa * 8)  = pxa;
        *(bf16x8a*)(yr + 96 + qa * 8)  = pxc;
    }
    __syncthreads();                                // B1: edge ready

    // ---- phase 1a: h1 MFMA — wave w owns cols [w*64, w*64+64); 16 chains
    f32x4 acc[4][4];
#pragma unroll
    for (int n = 0; n < 4; ++n) {
        float bv = b1[w * 64 + n * 16 + c16];
#pragma unroll
        for (int m = 0; m < 4; ++m) acc[m][n] = (f32x4){bv, bv, bv, bv};
    }
    {
        const short* w1p = W1T + (size_t)(w * 64 + c16) * 192 + qa * 8;
#pragma unroll
        for (int t = 0; t < 6; ++t) {
            bf16x8 av[4], bw[4];
#pragma unroll
            for (int m = 0; m < 4; ++m)
                av[m] = *(const bf16x8a*)(s_h + (m * 16 + c16) * 264 + t * 32 + qa * 8);
#pragma unroll
            for (int n = 0; n < 4; ++n)
                bw[n] = *(const bf16x8a*)(w1p + (size_t)n * 3072 + t * 32);
#pragma unroll
            for (int m = 0; m < 4; ++m)
#pragma unroll
                for (int n = 0; n < 4; ++n)
                    acc[m][n] = MFMA16(av[m], bw[n], acc[m][n]);
        }
    }
    __syncthreads();                                // B2: all edge reads done

    // ---- phase 1b: write h1 (bf16) into s_h, cols w*64..w*64+64, all rows
#pragma unroll
    for (int m = 0; m < 4; ++m)
#pragma unroll
        for (int n = 0; n < 4; ++n)
#pragma unroll
            for (int r = 0; r < 4; ++r)
                s_h[(m * 16 + qa * 4 + r) * 264 + w * 64 + n * 16 + c16] =
                    f2b(fmaxf(acc[m][n][r], 0.f));
    __syncthreads();                                // B3: full h1 ready

    // ---- phase 2: h2 per-point (rows w*16.., K=256) -> s_y cols 32..63
    {
        f32x4 hacc[2];
        float h0 = b2[c16], h1v = b2[16 + c16];
        hacc[0] = (f32x4){h0, h0, h0, h0};
        hacc[1] = (f32x4){h1v, h1v, h1v, h1v};
#pragma unroll
        for (int t = 0; t < 8; ++t) {
            bf16x8 am = *(const bf16x8a*)(s_h + (w * 16 + c16) * 264 + t * 32 + qa * 8);
            bf16x8 wb0 = *(const bf16x8a*)(W2T + (size_t)c16 * 256 + t * 32 + qa * 8);
            bf16x8 wb1 = *(const bf16x8a*)(W2T + (size_t)(16 + c16) * 256 + t * 32 + qa * 8);
            hacc[0] = MFMA16(am, wb0, hacc[0]);
            hacc[1] = MFMA16(am, wb1, hacc[1]);
        }
#pragma unroll
        for (int n2 = 0; n2 < 2; ++n2)
#pragma unroll
            for (int r = 0; r < 4; ++r)
                s_y[(w * 16 + qa * 4 + r) * 136 + 32 + n2 * 16 + c16] =
                    f2b(fmaxf(hacc[n2][r], 0.f));
    }

    // ---- phase 3: mid (own point, K=96 over [h2|x]) -> s_y cols 0..31
    {
        f32x4 macc[2];
        float m0 = bmid[c16], m1 = bmid[16 + c16];
        macc[0] = (f32x4){m0, m0, m0, m0};
        macc[1] = (f32x4){m1, m1, m1, m1};
#pragma unroll
        for (int t = 0; t < 3; ++t) {
            bf16x8 av = *(const bf16x8a*)(s_y + (w * 16 + c16) * 136 + 32 + t * 32 + qa * 8);
            bf16x8 wb0 = *(const bf16x8a*)(WmidT + (size_t)c16 * 96 + t * 32 + qa * 8);
            bf16x8 wb1 = *(const bf16x8a*)(WmidT + (size_t)(16 + c16) * 96 + t * 32 + qa * 8);
            macc[0] = MFMA16(av, wb0, macc[0]);
            macc[1] = MFMA16(av, wb1, macc[1]);
        }
#pragma unroll
        for (int n2 = 0; n2 < 2; ++n2)
#pragma unroll
            for (int r = 0; r < 4; ++r)
                s_y[(w * 16 + qa * 4 + r) * 136 + n2 * 16 + c16] =
                    f2b(fmaxf(macc[n2][r], 0.f));
    }
    __syncthreads();                                // B3b: mid fully written

    // ---- phase 4: ym = mean over k (own point) — SHORT loads/stores only
    {
        float s0 = 0.f, s1 = 0.f;
#pragma unroll
        for (int k = 0; k < 16; ++k) {
            const short* yp = s_y + (w * 16 + k) * 136;
            s0 += b2f(yp[2 * l]);
            s1 += b2f(yp[2 * l + 1]);
        }
        s_ym[w * 128 + 2 * l]     = f2b(s0 * 0.0625f);
        s_ym[w * 128 + 2 * l + 1] = f2b(s1 * 0.0625f);
    }
    __syncthreads();                                // B4: all 4 points' ym ready

    // ---- phase 5: gate — one M-tile (rows = points), wave w owns cols w*32..
    {
        f32x4 gacc[2];
        float g0 = bg[w * 32 + c16], g1 = bg[w * 32 + 16 + c16];
        gacc[0] = (f32x4){g0, g0, g0, g0};
        gacc[1] = (f32x4){g1, g1, g1, g1};
#pragma unroll
        for (int t = 0; t < 4; ++t) {
            bf16x8 av = *(const bf16x8a*)(s_ym + (c16 & 3) * 128 + t * 32 + qa * 8);
            bf16x8 wb0 = *(const bf16x8a*)(WgT + (size_t)(w * 32 + c16) * 128 + t * 32 + qa * 8);
            bf16x8 wb1 = *(const bf16x8a*)(WgT + (size_t)(w * 32 + 16 + c16) * 128 + t * 32 + qa * 8);
            gacc[0] = MFMA16(av, wb0, gacc[0]);
            gacc[1] = MFMA16(av, wb1, gacc[1]);
        }
        if (qa == 0) {
#pragma unroll
            for (int n2 = 0; n2 < 2; ++n2)
#pragma unroll
                for (int r = 0; r < 4; ++r)
                    s_gate[r][w * 32 + n2 * 16 + c16] =
                        1.0f / (1.0f + __expf(-gacc[n2][r]));
        }
    }
    __syncthreads();                                // B5: gates ready

    // ---- phase 6: y *= gate (in place, SHORT ops), fused y-max + store
    {
        float g0 = s_gate[w][2 * l], g1 = s_gate[w][2 * l + 1];
        float m0 = -__uint_as_float(0x7F800000u), m1 = m0;
#pragma unroll
        for (int k = 0; k < 16; ++k) {
            short* yp = s_y + (w * 16 + k) * 136;
            float v0 = b2f(yp[2 * l]) * g0;
            float v1 = b2f(yp[2 * l + 1]) * g1;
            m0 = fmaxf(m0, v0);
            m1 = fmaxf(m1, v1);
            yp[2 * l]     = f2b(v0);
            yp[2 * l + 1] = f2b(v1);
        }
        float2 st; st.x = m0; st.y = m1;
        *(float2*)(out + (size_t)p * 160 + 32 + 2 * l) = st;
    }
    __syncthreads();                                // B6: gated y fully written

    // ---- phase 7: z = y_gated @ Wlast + blast; max over k; store ch 0..31
    {
        f32x4 zacc[2];
        float z0 = blast[c16], z1 = blast[16 + c16];
        zacc[0] = (f32x4){z0, z0, z0, z0};
        zacc[1] = (f32x4){z1, z1, z1, z1};
#pragma unroll
        for (int t = 0; t < 4; ++t) {
            bf16x8 av = *(const bf16x8a*)(s_y + (w * 16 + c16) * 136 + t * 32 + qa * 8);
            bf16x8 wb0 = *(const bf16x8a*)(WlastT + (size_t)c16 * 128 + t * 32 + qa * 8);
            bf16x8 wb1 = *(const bf16x8a*)(WlastT + (size_t)(16 + c16) * 128 + t * 32 + qa * 8);
            zacc[0] = MFMA16(av, wb0, zacc[0]);
            zacc[1] = MFMA16(av, wb1, zacc[1]);
        }
#pragma unroll
        for (int nt = 0; nt < 2; ++nt) {
            float m = fmaxf(fmaxf(zacc[nt][0], zacc[nt][1]),
                            fmaxf(zacc[nt][2], zacc[nt][3]));
            m = fmaxf(m, __shfl_xor(m, 16));
            m = fmaxf(m, __shfl_xor(m, 32));
            if (l < 16) out[(size_t)p * 160 + nt * 16 + l] = m;
        }
    }
}

extern "C" void kernel_launch(void* const* d_in, const int* in_sizes, int n_in,
                              void* d_out, int out_size, void* d_ws, size_t ws_size,
                              hipStream_t stream) {
    const float* x     = (const float*)d_in[0];
    const float* pos   = (const float*)d_in[1];
    const float* W1    = (const float*)d_in[2];
    const float* b1    = (const float*)d_in[3];
    const float* W2    = (const float*)d_in[4];
    const float* b2    = (const float*)d_in[5];
    const float* Wmid  = (const float*)d_in[6];
    const float* bmid  = (const float*)d_in[7];
    const float* Wg    = (const float*)d_in[8];
    const float* bg    = (const float*)d_in[9];
    const float* Wlast = (const float*)d_in[10];
    const float* blast = (const float*)d_in[11];
    float* out = (float*)d_out;

    char* ws = (char*)d_ws;
    int*    idx    = (int*)(ws + 0);              // 2,097,152 B
    float4* pq     = (float4*)(ws + 2097152);     // 524,288 B
    short*  W1T    = (short*)(ws + 2621440);      // 98,304 B
    short*  W2T    = (short*)(ws + 2719744);      // 16,384 B
    short*  WmidT  = (short*)(ws + 2736128);      // 6,144 B
    short*  WlastT = (short*)(ws + 2742272);      // 8,192 B
    short*  WgT    = (short*)(ws + 2750464);      // 32,768 B

    prep_kernel<<<dim3(444), dim3(256), 0, stream>>>(
        pos, W1, W2, Wmid, Wlast, Wg, pq, W1T, W2T, WmidT, WlastT, WgT);
    knn4_kernel<<<dim3(BB * NN / 4), dim3(256), 0, stream>>>(pq, idx);
    fused5_kernel<<<dim3(BB * NN / 4), dim3(256), 0, stream>>>(
        x, idx, W1T, W2T, WmidT, WlastT, WgT, b1, b2, bmid, bg, blast, out);
}